// Round 1
// baseline (1395.425 us; speedup 1.0000x reference)
//
#include <hip/hip_runtime.h>

typedef unsigned short u16;
typedef unsigned int u32;
typedef __attribute__((ext_vector_type(4))) float f32x4;
typedef __attribute__((ext_vector_type(8))) short short8;
typedef __attribute__((ext_vector_type(4))) short short4v;

#define HIDDEN 2048
#define NHEADS 16
#define KEYDIM 1024
#define VALDIM 2048
#define HEADK 64
#define HEADV 128
#define NBATCH 8
#define SEQ 4096
#define NTOK (NBATCH * SEQ)

__device__ __forceinline__ u16 f2bf(float f) {
  union { float f; u32 u; } c; c.f = f;
  u32 r = c.u + 0x7FFFu + ((c.u >> 16) & 1u);
  return (u16)(r >> 16);
}
__device__ __forceinline__ float bf2f(u16 h) {
  union { u32 u; float f; } c; c.u = ((u32)h) << 16;
  return c.f;
}

// ---------------- weight cast f32 -> bf16 ----------------
__global__ __launch_bounds__(256) void cast_bf16_k(const float* __restrict__ in,
                                                   u16* __restrict__ out, int n4) {
  int i = blockIdx.x * blockDim.x + threadIdx.x;
  if (i >= n4) return;
  f32x4 v = *(const f32x4*)(in + (size_t)i * 4);
  short4v o;
  o[0] = (short)f2bf(v[0]); o[1] = (short)f2bf(v[1]);
  o[2] = (short)f2bf(v[2]); o[3] = (short)f2bf(v[3]);
  *(short4v*)(out + (size_t)i * 4) = o;
}

// ---------------- K1: RMSNorm(hidden) -> bf16 ----------------
__global__ __launch_bounds__(256) void rmsnorm_cast_k(const float* __restrict__ x,
                                                      const float* __restrict__ w,
                                                      u16* __restrict__ xb) {
  int r = blockIdx.x;
  int tid = threadIdx.x;
  const float* xp = x + (size_t)r * HIDDEN + tid * 8;
  f32x4 v0 = *(const f32x4*)xp;
  f32x4 v1 = *(const f32x4*)(xp + 4);
  float ss = v0[0]*v0[0]+v0[1]*v0[1]+v0[2]*v0[2]+v0[3]*v0[3]
           + v1[0]*v1[0]+v1[1]*v1[1]+v1[2]*v1[2]+v1[3]*v1[3];
  #pragma unroll
  for (int m = 32; m >= 1; m >>= 1) ss += __shfl_xor(ss, m);
  __shared__ float red[4];
  if ((tid & 63) == 0) red[tid >> 6] = ss;
  __syncthreads();
  float tot = red[0] + red[1] + red[2] + red[3];
  float inv = rsqrtf(tot * (1.0f / HIDDEN) + 1e-5f);
  const float* wp = w + tid * 8;
  f32x4 w0 = *(const f32x4*)wp;
  f32x4 w1 = *(const f32x4*)(wp + 4);
  short8 o;
  o[0] = (short)f2bf(v0[0] * inv * w0[0]);
  o[1] = (short)f2bf(v0[1] * inv * w0[1]);
  o[2] = (short)f2bf(v0[2] * inv * w0[2]);
  o[3] = (short)f2bf(v0[3] * inv * w0[3]);
  o[4] = (short)f2bf(v1[0] * inv * w1[0]);
  o[5] = (short)f2bf(v1[1] * inv * w1[1]);
  o[6] = (short)f2bf(v1[2] * inv * w1[2]);
  o[7] = (short)f2bf(v1[3] * inv * w1[3]);
  *(short8*)(xb + (size_t)r * HIDDEN + tid * 8) = o;
}

// ---------------- GEMM C[M,N] = A[M,K] @ B[N,K]^T (bf16, m97 structure) ----------------
#define BM 128
#define BN 128
#define BK 32

__device__ __forceinline__ void gload16(const u16* g, u16* l) {
  __builtin_amdgcn_global_load_lds((const __attribute__((address_space(1))) void*)g,
                                   (__attribute__((address_space(3))) void*)l, 16, 0, 0);
}

// MODE 0: store bf16.  MODE 1: store sigmoid(v) as f32.  MODE 2: out[idx] *= v (f32 RMW).
template <int MODE>
__global__ __launch_bounds__(256) void gemm_bt_k(const u16* __restrict__ A,
                                                 const u16* __restrict__ Bw,
                                                 void* __restrict__ Cptr,
                                                 int M, int N, int K) {
  __shared__ u16 As[BM * BK];
  __shared__ u16 Bs[BN * BK];
  int tid = threadIdx.x;
  int bm = blockIdx.x, bn = blockIdx.y;
  int w = tid >> 6, l = tid & 63;
  int wm = w >> 1, wn = w & 1;
  int lr = l & 15, kq = l >> 4;

  const u16* Ag = A + (size_t)bm * BM * K;
  const u16* Bg = Bw + (size_t)bn * BN * K;

  int r0 = tid >> 2;            // rows 0..63 (chunk tid), +64 for chunk tid+256
  int koff = (tid & 3) * 8;     // k element offset within the 32-wide tile

  f32x4 acc[4][4] = {};

  for (int k0 = 0; k0 < K; k0 += BK) {
    gload16(Ag + (size_t)r0 * K + k0 + koff, As + tid * 8);
    gload16(Ag + (size_t)(r0 + 64) * K + k0 + koff, As + (tid + 256) * 8);
    gload16(Bg + (size_t)r0 * K + k0 + koff, Bs + tid * 8);
    gload16(Bg + (size_t)(r0 + 64) * K + k0 + koff, Bs + (tid + 256) * 8);
    asm volatile("s_waitcnt vmcnt(0)" ::: "memory");
    __syncthreads();

    short8 af[4], bf[4];
    #pragma unroll
    for (int m = 0; m < 4; ++m)
      af[m] = *(const short8*)(As + (wm * 64 + m * 16 + lr) * BK + kq * 8);
    #pragma unroll
    for (int n = 0; n < 4; ++n)
      bf[n] = *(const short8*)(Bs + (wn * 64 + n * 16 + lr) * BK + kq * 8);
    #pragma unroll
    for (int m = 0; m < 4; ++m) {
      #pragma unroll
      for (int n = 0; n < 4; ++n)
        acc[m][n] = __builtin_amdgcn_mfma_f32_16x16x32_bf16(af[m], bf[n], acc[m][n], 0, 0, 0);
    }
    __syncthreads();
  }

  #pragma unroll
  for (int m = 0; m < 4; ++m) {
    #pragma unroll
    for (int n = 0; n < 4; ++n) {
      #pragma unroll
      for (int j = 0; j < 4; ++j) {
        int row = bm * BM + wm * 64 + m * 16 + kq * 4 + j;
        int col = bn * BN + wn * 64 + n * 16 + lr;
        size_t idx = (size_t)row * N + col;
        float v = acc[m][n][j];
        if constexpr (MODE == 0) {
          ((u16*)Cptr)[idx] = f2bf(v);
        } else if constexpr (MODE == 1) {
          ((float*)Cptr)[idx] = 1.0f / (1.0f + __expf(-v));
        } else {
          float* O = (float*)Cptr;
          O[idx] = O[idx] * v;
        }
      }
    }
  }
}

// ---------------- K3: L2-normalize(q head) @ S[b,h] -> RMSNorm -> bf16 o_mid ----------------
__global__ __launch_bounds__(256) void glaread_k(const u16* __restrict__ q,
                                                 const float* __restrict__ S,
                                                 const float* __restrict__ vw,
                                                 u16* __restrict__ omid) {
  int bh = blockIdx.x;             // b*16 + h
  int b = bh >> 4, h = bh & 15;
  int tid = threadIdx.x;
  int w = tid >> 6, l = tid & 63;
  int lr = l & 15, kq = l >> 4;

  // Register-resident B fragments of S[b,h] (64x128 -> MFMA B layout, bf16)
  const float* Sp = S + (size_t)bh * HEADK * HEADV;
  short8 bfrag[8][2];
  #pragma unroll
  for (int n = 0; n < 8; ++n) {
    #pragma unroll
    for (int s = 0; s < 2; ++s) {
      #pragma unroll
      for (int i = 0; i < 8; ++i)
        bfrag[n][s][i] =
            (short)f2bf(Sp[(size_t)(s * 32 + kq * 8 + i) * HEADV + n * 16 + lr]);
    }
  }
  float vwn[8];
  #pragma unroll
  for (int n = 0; n < 8; ++n) vwn[n] = vw[n * 16 + lr];

  #pragma unroll 1
  for (int it = 0; it < 8; ++it) {
    int t0 = blockIdx.y * 512 + it * 64 + w * 16;   // 16 tokens per wave
    const u16* qp = q + (size_t)(b * SEQ + t0 + lr) * KEYDIM + h * HEADK;
    short8 a0 = *(const short8*)(qp + kq * 8);
    short8 a1 = *(const short8*)(qp + 32 + kq * 8);

    // L2 norm over 64 (reduce across the 4 kq groups)
    float ss = 0.f;
    #pragma unroll
    for (int i = 0; i < 8; ++i) {
      float x0 = bf2f((u16)a0[i]), x1 = bf2f((u16)a1[i]);
      ss += x0 * x0 + x1 * x1;
    }
    ss += __shfl_xor(ss, 16);
    ss += __shfl_xor(ss, 32);
    float sc = 1.0f / fmaxf(sqrtf(ss), 1e-12f);

    short8 an0, an1;
    #pragma unroll
    for (int i = 0; i < 8; ++i) {
      an0[i] = (short)f2bf(bf2f((u16)a0[i]) * sc);
      an1[i] = (short)f2bf(bf2f((u16)a1[i]) * sc);
    }

    f32x4 acc[8] = {};
    #pragma unroll
    for (int n = 0; n < 8; ++n) {
      acc[n] = __builtin_amdgcn_mfma_f32_16x16x32_bf16(an0, bfrag[n][0], acc[n], 0, 0, 0);
      acc[n] = __builtin_amdgcn_mfma_f32_16x16x32_bf16(an1, bfrag[n][1], acc[n], 0, 0, 0);
    }

    // RMSNorm over V=128 (lane-local over n, then reduce across the 16 lr lanes)
    float part[4] = {0.f, 0.f, 0.f, 0.f};
    #pragma unroll
    for (int n = 0; n < 8; ++n) {
      #pragma unroll
      for (int j = 0; j < 4; ++j) part[j] += acc[n][j] * acc[n][j];
    }
    #pragma unroll
    for (int msk = 1; msk <= 8; msk <<= 1) {
      #pragma unroll
      for (int j = 0; j < 4; ++j) part[j] += __shfl_xor(part[j], msk);
    }
    #pragma unroll
    for (int j = 0; j < 4; ++j) {
      float inv = rsqrtf(part[j] * (1.0f / HEADV) + 1e-5f);
      int tok = t0 + kq * 4 + j;
      u16* op = omid + (size_t)(b * SEQ + tok) * VALDIM + h * HEADV;
      #pragma unroll
      for (int n = 0; n < 8; ++n)
        op[n * 16 + lr] = f2bf(acc[n][j] * inv * vwn[n]);
    }
  }
}

extern "C" void kernel_launch(void* const* d_in, const int* in_sizes, int n_in,
                              void* d_out, int out_size, void* d_ws, size_t ws_size,
                              hipStream_t stream) {
  const float* hs = (const float*)d_in[0];   // (8,4096,2048)
  const float* S  = (const float*)d_in[1];   // (8,16,64,128)
  const float* nw = (const float*)d_in[2];   // (2048)
  const float* qw = (const float*)d_in[3];   // (1024,2048)
  const float* vw = (const float*)d_in[4];   // (128)
  const float* ow = (const float*)d_in[5];   // (2048,2048)
  const float* gw = (const float*)d_in[6];   // (2048,2048)
  float* out = (float*)d_out;

  u16* xb   = (u16*)d_ws;                             // NTOK*2048 bf16
  u16* q    = xb + (size_t)NTOK * HIDDEN;             // NTOK*1024 bf16
  u16* qwb  = q + (size_t)NTOK * KEYDIM;              // 1024*2048
  u16* owb  = qwb + (size_t)KEYDIM * HIDDEN;          // 2048*2048
  u16* gwb  = owb + (size_t)HIDDEN * VALDIM;          // 2048*2048
  u16* omid = xb;  // reuse xb after gate GEMM has consumed it

  // weight casts
  cast_bf16_k<<<(KEYDIM * HIDDEN / 4 + 255) / 256, 256, 0, stream>>>(qw, qwb, KEYDIM * HIDDEN / 4);
  cast_bf16_k<<<(HIDDEN * VALDIM / 4 + 255) / 256, 256, 0, stream>>>(ow, owb, HIDDEN * VALDIM / 4);
  cast_bf16_k<<<(HIDDEN * HIDDEN / 4 + 255) / 256, 256, 0, stream>>>(gw, gwb, HIDDEN * HIDDEN / 4);

  // x = rmsnorm(hidden) -> bf16
  rmsnorm_cast_k<<<NTOK, 256, 0, stream>>>(hs, nw, xb);

  // q = x @ q_w^T  (bf16 out)
  gemm_bt_k<0><<<dim3(NTOK / BM, KEYDIM / BN), 256, 0, stream>>>(xb, qwb, q, NTOK, KEYDIM, HIDDEN);

  // out = sigmoid(x @ gate_w^T)  (f32)
  gemm_bt_k<1><<<dim3(NTOK / BM, HIDDEN / BN), 256, 0, stream>>>(xb, gwb, out, NTOK, HIDDEN, HIDDEN);

  // o_mid = rmsnorm_v( l2norm(q_head) @ S[b,h] )  (bf16, overwrites xb)
  glaread_k<<<dim3(NBATCH * NHEADS, SEQ / 512), 256, 0, stream>>>(q, S, vw, omid);

  // out *= o_mid @ o_w^T
  gemm_bt_k<2><<<dim3(NTOK / BM, HIDDEN / BN), 256, 0, stream>>>(omid, owb, out, NTOK, HIDDEN, VALDIM);
}

// Round 2
// 999.911 us; speedup vs baseline: 1.3955x; 1.3955x over previous
//
#include <hip/hip_runtime.h>

typedef unsigned short u16;
typedef unsigned int u32;
typedef __attribute__((ext_vector_type(4))) float f32x4;
typedef __attribute__((ext_vector_type(8))) short short8;
typedef __attribute__((ext_vector_type(4))) short short4v;

#define HIDDEN 2048
#define NHEADS 16
#define KEYDIM 1024
#define VALDIM 2048
#define HEADK 64
#define HEADV 128
#define NBATCH 8
#define SEQ 4096
#define NTOK (NBATCH * SEQ)

__device__ __forceinline__ u16 f2bf(float f) {
  union { float f; u32 u; } c; c.f = f;
  u32 r = c.u + 0x7FFFu + ((c.u >> 16) & 1u);
  return (u16)(r >> 16);
}
__device__ __forceinline__ float bf2f(u16 h) {
  union { u32 u; float f; } c; c.u = ((u32)h) << 16;
  return c.f;
}

// ---------------- weight cast f32 -> bf16 ----------------
__global__ __launch_bounds__(256) void cast_bf16_k(const float* __restrict__ in,
                                                   u16* __restrict__ out, int n4) {
  int i = blockIdx.x * blockDim.x + threadIdx.x;
  if (i >= n4) return;
  f32x4 v = *(const f32x4*)(in + (size_t)i * 4);
  short4v o;
  o[0] = (short)f2bf(v[0]); o[1] = (short)f2bf(v[1]);
  o[2] = (short)f2bf(v[2]); o[3] = (short)f2bf(v[3]);
  *(short4v*)(out + (size_t)i * 4) = o;
}

// ---------------- K1: RMSNorm(hidden) -> bf16 ----------------
__global__ __launch_bounds__(256) void rmsnorm_cast_k(const float* __restrict__ x,
                                                      const float* __restrict__ w,
                                                      u16* __restrict__ xb) {
  int r = blockIdx.x;
  int tid = threadIdx.x;
  const float* xp = x + (size_t)r * HIDDEN + tid * 8;
  f32x4 v0 = *(const f32x4*)xp;
  f32x4 v1 = *(const f32x4*)(xp + 4);
  float ss = v0[0]*v0[0]+v0[1]*v0[1]+v0[2]*v0[2]+v0[3]*v0[3]
           + v1[0]*v1[0]+v1[1]*v1[1]+v1[2]*v1[2]+v1[3]*v1[3];
  #pragma unroll
  for (int m = 32; m >= 1; m >>= 1) ss += __shfl_xor(ss, m);
  __shared__ float red[4];
  if ((tid & 63) == 0) red[tid >> 6] = ss;
  __syncthreads();
  float tot = red[0] + red[1] + red[2] + red[3];
  float inv = rsqrtf(tot * (1.0f / HIDDEN) + 1e-5f);
  const float* wp = w + tid * 8;
  f32x4 w0 = *(const f32x4*)wp;
  f32x4 w1 = *(const f32x4*)(wp + 4);
  short8 o;
  o[0] = (short)f2bf(v0[0] * inv * w0[0]);
  o[1] = (short)f2bf(v0[1] * inv * w0[1]);
  o[2] = (short)f2bf(v0[2] * inv * w0[2]);
  o[3] = (short)f2bf(v0[3] * inv * w0[3]);
  o[4] = (short)f2bf(v1[0] * inv * w1[0]);
  o[5] = (short)f2bf(v1[1] * inv * w1[1]);
  o[6] = (short)f2bf(v1[2] * inv * w1[2]);
  o[7] = (short)f2bf(v1[3] * inv * w1[3]);
  *(short8*)(xb + (size_t)r * HIDDEN + tid * 8) = o;
}

// ---------------- 256x256 GEMM, BK=32, 4-buffer depth-3 pipeline ----------------
// C[M,N] = A[M,K] @ B[N,K]^T, bf16 in, modes: 0 bf16 store, 1 sigmoid f32, 2 f32 RMW *=

__device__ __forceinline__ void gload16(const u16* g, u16* l) {
  __builtin_amdgcn_global_load_lds((const __attribute__((address_space(1))) void*)g,
                                   (__attribute__((address_space(3))) void*)l, 16, 0, 0);
}

// per-buffer: A 256x32 u16 (8192) + B 256x32 u16 (8192) = 16384 u16 = 32 KB
#define BUF_U16 16384
#define NBUF 4

template <int MODE>
__global__ __launch_bounds__(512, 2) void gemm256_k(const u16* __restrict__ A,
                                                    const u16* __restrict__ Bw,
                                                    void* __restrict__ Cptr,
                                                    int M, int N, int K) {
  extern __shared__ u16 lds[];
  const int tid = threadIdx.x;
  const int wid = tid >> 6;
  const int wm = wid >> 2;          // 0..1
  const int wn = wid & 3;           // 0..3
  const int l = tid & 63;
  const int lr = l & 15;
  const int kq = l >> 4;

  // XCD-aware swizzle + N-tile-fastest decomposition
  const int ntn = N >> 8;
  const int per = gridDim.x >> 3;
  const int b = blockIdx.x;
  const int s = (b & 7) * per + (b >> 3);
  const int mt = s / ntn;
  const int nt = s - mt * ntn;

  const u16* Ag = A + (size_t)mt * 256 * K;
  const u16* Bg = Bw + (size_t)nt * 256 * K;

  // staging geometry: per load-instr 512 thr x 16B = 128 rows x 64B
  const int srow = tid >> 2;                              // 0..127
  const int kel = (((tid & 3) ^ ((tid >> 3) & 3)) << 3);  // swizzled k-chunk (elements)
  u16* dA0 = lds + tid * 8;
  u16* dA1 = lds + (512 + tid) * 8;
  u16* dB0 = lds + 8192 + tid * 8;
  u16* dB1 = lds + 8192 + (512 + tid) * 8;

  const int NT = K >> 5;

#define STAGE(t)                                                        \
  do {                                                                  \
    int _off = (int)(((t) & 3) * BUF_U16);                              \
    int _k0 = (t) << 5;                                                 \
    const u16* _as = Ag + (size_t)srow * K + _k0 + kel;                 \
    gload16(_as, dA0 + _off);                                           \
    gload16(_as + (size_t)128 * K, dA1 + _off);                         \
    const u16* _bs = Bg + (size_t)srow * K + _k0 + kel;                 \
    gload16(_bs, dB0 + _off);                                           \
    gload16(_bs + (size_t)128 * K, dB1 + _off);                         \
  } while (0)

  STAGE(0);
  STAGE(1);
  STAGE(2);

  f32x4 acc[8][4] = {};

  for (int t = 0; t < NT; ++t) {
    if (t + 2 < NT)      asm volatile("s_waitcnt vmcnt(8)" ::: "memory");
    else if (t + 1 < NT) asm volatile("s_waitcnt vmcnt(4)" ::: "memory");
    else                 asm volatile("s_waitcnt vmcnt(0)" ::: "memory");
    __builtin_amdgcn_s_barrier();
    asm volatile("" ::: "memory");
    __builtin_amdgcn_sched_barrier(0);

    if (t + 3 < NT) STAGE(t + 3);

    const u16* bufA = lds + (size_t)(t & 3) * BUF_U16;
    const u16* bufB = bufA + 8192;

    short8 bfr[4], afr[8];
    #pragma unroll
    for (int n = 0; n < 4; ++n) {
      int R = wn * 64 + n * 16 + lr;
      bfr[n] = *(const short8*)(bufB + R * 32 + ((kq ^ ((R >> 1) & 3)) << 3));
    }
    #pragma unroll
    for (int m = 0; m < 8; ++m) {
      int R = wm * 128 + m * 16 + lr;
      afr[m] = *(const short8*)(bufA + R * 32 + ((kq ^ ((R >> 1) & 3)) << 3));
    }
    __builtin_amdgcn_s_setprio(1);
    #pragma unroll
    for (int m = 0; m < 8; ++m) {
      #pragma unroll
      for (int n = 0; n < 4; ++n)
        acc[m][n] = __builtin_amdgcn_mfma_f32_16x16x32_bf16(afr[m], bfr[n], acc[m][n], 0, 0, 0);
    }
    __builtin_amdgcn_s_setprio(0);
  }
#undef STAGE

  const int rowB = mt * 256 + wm * 128 + kq * 4;
  const int colB = nt * 256 + wn * 64 + lr;
  #pragma unroll
  for (int m = 0; m < 8; ++m) {
    #pragma unroll
    for (int n = 0; n < 4; ++n) {
      #pragma unroll
      for (int j = 0; j < 4; ++j) {
        int row = rowB + m * 16 + j;
        int col = colB + n * 16;
        size_t idx = (size_t)row * N + col;
        float v = acc[m][n][j];
        if constexpr (MODE == 0) {
          ((u16*)Cptr)[idx] = f2bf(v);
        } else if constexpr (MODE == 1) {
          ((float*)Cptr)[idx] = 1.0f / (1.0f + __expf(-v));
        } else {
          float* O = (float*)Cptr;
          O[idx] = O[idx] * v;
        }
      }
    }
  }
}

// ---------------- K3: L2-normalize(q head) @ S[b,h] -> RMSNorm -> bf16 o_mid ----------------
__global__ __launch_bounds__(256) void glaread_k(const u16* __restrict__ q,
                                                 const float* __restrict__ S,
                                                 const float* __restrict__ vw,
                                                 u16* __restrict__ omid) {
  int bh = blockIdx.x;             // b*16 + h
  int b = bh >> 4, h = bh & 15;
  int tid = threadIdx.x;
  int w = tid >> 6, l = tid & 63;
  int lr = l & 15, kq = l >> 4;

  const float* Sp = S + (size_t)bh * HEADK * HEADV;
  short8 bfrag[8][2];
  #pragma unroll
  for (int n = 0; n < 8; ++n) {
    #pragma unroll
    for (int s = 0; s < 2; ++s) {
      #pragma unroll
      for (int i = 0; i < 8; ++i)
        bfrag[n][s][i] =
            (short)f2bf(Sp[(size_t)(s * 32 + kq * 8 + i) * HEADV + n * 16 + lr]);
    }
  }
  float vwn[8];
  #pragma unroll
  for (int n = 0; n < 8; ++n) vwn[n] = vw[n * 16 + lr];

  #pragma unroll 1
  for (int it = 0; it < 8; ++it) {
    int t0 = blockIdx.y * 512 + it * 64 + w * 16;
    const u16* qp = q + (size_t)(b * SEQ + t0 + lr) * KEYDIM + h * HEADK;
    short8 a0 = *(const short8*)(qp + kq * 8);
    short8 a1 = *(const short8*)(qp + 32 + kq * 8);

    float ss = 0.f;
    #pragma unroll
    for (int i = 0; i < 8; ++i) {
      float x0 = bf2f((u16)a0[i]), x1 = bf2f((u16)a1[i]);
      ss += x0 * x0 + x1 * x1;
    }
    ss += __shfl_xor(ss, 16);
    ss += __shfl_xor(ss, 32);
    float sc = 1.0f / fmaxf(sqrtf(ss), 1e-12f);

    short8 an0, an1;
    #pragma unroll
    for (int i = 0; i < 8; ++i) {
      an0[i] = (short)f2bf(bf2f((u16)a0[i]) * sc);
      an1[i] = (short)f2bf(bf2f((u16)a1[i]) * sc);
    }

    f32x4 acc[8] = {};
    #pragma unroll
    for (int n = 0; n < 8; ++n) {
      acc[n] = __builtin_amdgcn_mfma_f32_16x16x32_bf16(an0, bfrag[n][0], acc[n], 0, 0, 0);
      acc[n] = __builtin_amdgcn_mfma_f32_16x16x32_bf16(an1, bfrag[n][1], acc[n], 0, 0, 0);
    }

    float part[4] = {0.f, 0.f, 0.f, 0.f};
    #pragma unroll
    for (int n = 0; n < 8; ++n) {
      #pragma unroll
      for (int j = 0; j < 4; ++j) part[j] += acc[n][j] * acc[n][j];
    }
    #pragma unroll
    for (int msk = 1; msk <= 8; msk <<= 1) {
      #pragma unroll
      for (int j = 0; j < 4; ++j) part[j] += __shfl_xor(part[j], msk);
    }
    #pragma unroll
    for (int j = 0; j < 4; ++j) {
      float inv = rsqrtf(part[j] * (1.0f / HEADV) + 1e-5f);
      int tok = t0 + kq * 4 + j;
      u16* op = omid + (size_t)(b * SEQ + tok) * VALDIM + h * HEADV;
      #pragma unroll
      for (int n = 0; n < 8; ++n)
        op[n * 16 + lr] = f2bf(acc[n][j] * inv * vwn[n]);
    }
  }
}

extern "C" void kernel_launch(void* const* d_in, const int* in_sizes, int n_in,
                              void* d_out, int out_size, void* d_ws, size_t ws_size,
                              hipStream_t stream) {
  const float* hs = (const float*)d_in[0];   // (8,4096,2048)
  const float* S  = (const float*)d_in[1];   // (8,16,64,128)
  const float* nw = (const float*)d_in[2];   // (2048)
  const float* qw = (const float*)d_in[3];   // (1024,2048)
  const float* vw = (const float*)d_in[4];   // (128)
  const float* ow = (const float*)d_in[5];   // (2048,2048)
  const float* gw = (const float*)d_in[6];   // (2048,2048)
  float* out = (float*)d_out;

  u16* xb   = (u16*)d_ws;                             // NTOK*2048 bf16
  u16* q    = xb + (size_t)NTOK * HIDDEN;             // NTOK*1024 bf16
  u16* qwb  = q + (size_t)NTOK * KEYDIM;              // 1024*2048
  u16* owb  = qwb + (size_t)KEYDIM * HIDDEN;          // 2048*2048
  u16* gwb  = owb + (size_t)HIDDEN * VALDIM;          // 2048*2048
  u16* omid = xb;  // reuse xb after gate GEMM has consumed it

  const size_t LDSB = (size_t)NBUF * BUF_U16 * sizeof(u16);  // 128 KiB

  // weight casts
  cast_bf16_k<<<(KEYDIM * HIDDEN / 4 + 255) / 256, 256, 0, stream>>>(qw, qwb, KEYDIM * HIDDEN / 4);
  cast_bf16_k<<<(HIDDEN * VALDIM / 4 + 255) / 256, 256, 0, stream>>>(ow, owb, HIDDEN * VALDIM / 4);
  cast_bf16_k<<<(HIDDEN * HIDDEN / 4 + 255) / 256, 256, 0, stream>>>(gw, gwb, HIDDEN * HIDDEN / 4);

  // x = rmsnorm(hidden) -> bf16
  rmsnorm_cast_k<<<NTOK, 256, 0, stream>>>(hs, nw, xb);

  // q = x @ q_w^T  (bf16 out)
  gemm256_k<0><<<dim3((NTOK / 256) * (KEYDIM / 256)), 512, LDSB, stream>>>(xb, qwb, q, NTOK, KEYDIM, HIDDEN);

  // out = sigmoid(x @ gate_w^T)  (f32)
  gemm256_k<1><<<dim3((NTOK / 256) * (HIDDEN / 256)), 512, LDSB, stream>>>(xb, gwb, out, NTOK, HIDDEN, HIDDEN);

  // o_mid = rmsnorm_v( l2norm(q_head) @ S[b,h] )  (bf16, overwrites xb)
  glaread_k<<<dim3(NBATCH * NHEADS, SEQ / 512), 256, 0, stream>>>(q, S, vw, omid);

  // out *= o_mid @ o_w^T
  gemm256_k<2><<<dim3((NTOK / 256) * (HIDDEN / 256)), 512, LDSB, stream>>>(omid, owb, out, NTOK, HIDDEN, VALDIM);
}

// Round 3
// 943.370 us; speedup vs baseline: 1.4792x; 1.0599x over previous
//
#include <hip/hip_runtime.h>

typedef unsigned short u16;
typedef unsigned int u32;
typedef __attribute__((ext_vector_type(4))) float f32x4;
typedef __attribute__((ext_vector_type(8))) short short8;
typedef __attribute__((ext_vector_type(4))) short short4v;

#define HIDDEN 2048
#define NHEADS 16
#define KEYDIM 1024
#define VALDIM 2048
#define HEADK 64
#define HEADV 128
#define NBATCH 8
#define SEQ 4096
#define NTOK (NBATCH * SEQ)

__device__ __forceinline__ u16 f2bf(float f) {
  union { float f; u32 u; } c; c.f = f;
  u32 r = c.u + 0x7FFFu + ((c.u >> 16) & 1u);
  return (u16)(r >> 16);
}
__device__ __forceinline__ float bf2f(u16 h) {
  union { u32 u; float f; } c; c.u = ((u32)h) << 16;
  return c.f;
}

// ---------------- weight cast f32 -> bf16 ----------------
__global__ __launch_bounds__(256) void cast_bf16_k(const float* __restrict__ in,
                                                   u16* __restrict__ out, int n4) {
  int i = blockIdx.x * blockDim.x + threadIdx.x;
  if (i >= n4) return;
  f32x4 v = *(const f32x4*)(in + (size_t)i * 4);
  short4v o;
  o[0] = (short)f2bf(v[0]); o[1] = (short)f2bf(v[1]);
  o[2] = (short)f2bf(v[2]); o[3] = (short)f2bf(v[3]);
  *(short4v*)(out + (size_t)i * 4) = o;
}

// ---------------- K1: RMSNorm(hidden) -> bf16 ----------------
__global__ __launch_bounds__(256) void rmsnorm_cast_k(const float* __restrict__ x,
                                                      const float* __restrict__ w,
                                                      u16* __restrict__ xb) {
  int r = blockIdx.x;
  int tid = threadIdx.x;
  const float* xp = x + (size_t)r * HIDDEN + tid * 8;
  f32x4 v0 = *(const f32x4*)xp;
  f32x4 v1 = *(const f32x4*)(xp + 4);
  float ss = v0[0]*v0[0]+v0[1]*v0[1]+v0[2]*v0[2]+v0[3]*v0[3]
           + v1[0]*v1[0]+v1[1]*v1[1]+v1[2]*v1[2]+v1[3]*v1[3];
  #pragma unroll
  for (int m = 32; m >= 1; m >>= 1) ss += __shfl_xor(ss, m);
  __shared__ float red[4];
  if ((tid & 63) == 0) red[tid >> 6] = ss;
  __syncthreads();
  float tot = red[0] + red[1] + red[2] + red[3];
  float inv = rsqrtf(tot * (1.0f / HIDDEN) + 1e-5f);
  const float* wp = w + tid * 8;
  f32x4 w0 = *(const f32x4*)wp;
  f32x4 w1 = *(const f32x4*)(wp + 4);
  short8 o;
  o[0] = (short)f2bf(v0[0] * inv * w0[0]);
  o[1] = (short)f2bf(v0[1] * inv * w0[1]);
  o[2] = (short)f2bf(v0[2] * inv * w0[2]);
  o[3] = (short)f2bf(v0[3] * inv * w0[3]);
  o[4] = (short)f2bf(v1[0] * inv * w1[0]);
  o[5] = (short)f2bf(v1[1] * inv * w1[1]);
  o[6] = (short)f2bf(v1[2] * inv * w1[2]);
  o[7] = (short)f2bf(v1[3] * inv * w1[3]);
  *(short8*)(xb + (size_t)r * HIDDEN + tid * 8) = o;
}

// ---------------- 256x256 GEMM, BK=64, 8-phase schedule (m201 port) ----------------
// C[M,N] = A[M,K] @ B[N,K]^T, bf16 in. MODE: 0 bf16 store, 1 sigmoid f32, 2 f32 RMW *=
// LDS: 2 K-tile buffers x (A 32KB + B 32KB) = 128 KB.  Buffer beta = ktile & 1.
//   A element (r,k): u16 idx = beta*32768 + r*64 + (((k>>3) ^ (r&7))<<3) + (k&7)
//   B element (r,k): same + 16384.
// Stage granularity: half-tile = 128 rows x 64 cols = 16KB = 2 global_load_lds/thread.
// Schedule per iteration i (computes K-tiles 2i [buf0, phases 0-3], 2i+1 [buf1, 4-7]):
//   p0: stage A(2i+1)h0   p1: A(2i+1)h1   p2: B(2i+2)h0   p3: B(2i+2)h1 + vmcnt(4)
//   p4: stage A(2i+2)h0   p5: A(2i+2)h1   p6: B(2i+3)h0   p7: B(2i+3)h1 + vmcnt(4)
// Slot freedom: B(c) slots free after p1-end barrier, A(c) after p2-end barrier
// (quadrant order q0=(m0-3,n0-1), q1=(m0-3,n2-3), q2=(m4-7,n2-3), q3=(m4-7,n0-1)).

__device__ __forceinline__ void gload16(const u16* g, u16* l) {
  __builtin_amdgcn_global_load_lds((const __attribute__((address_space(1))) void*)g,
                                   (__attribute__((address_space(3))) void*)l, 16, 0, 0);
}

#define BAR()                                  \
  do {                                         \
    __builtin_amdgcn_s_barrier();              \
    __builtin_amdgcn_sched_barrier(0);         \
  } while (0)

template <int MODE>
__global__ __launch_bounds__(512, 2) void gemm8p_k(const u16* __restrict__ A,
                                                   const u16* __restrict__ Bw,
                                                   void* __restrict__ Cptr,
                                                   int M, int N, int K) {
  extern __shared__ u16 lds[];
  const int tid = threadIdx.x;
  const int wid = tid >> 6;
  const int wm = wid >> 2;          // 0..1  (M half)
  const int wn = wid & 3;           // 0..3  (N quarter)
  const int l = tid & 63;
  const int lr = l & 15;
  const int kq = l >> 4;

  // XCD-aware bijective swizzle + N-tile-fastest
  const int ntn = N >> 8;
  const int per = gridDim.x >> 3;
  const int b = blockIdx.x;
  const int sidx = (b & 7) * per + (b >> 3);
  const int mt = sidx / ntn;
  const int nt = sidx - mt * ntn;

  const u16* Ag = A + (size_t)(mt * 256) * K;
  const u16* Bg = Bw + (size_t)(nt * 256) * K;

  // staging geometry: per load-instr 512 thr x 16B = 64 rows x 128B
  const int srow = tid >> 3;                    // 0..63
  const int schunk = (tid & 7) ^ (srow & 7);    // pre-swizzled source chunk

#define STAGE_A(c, h)                                                          \
  do {                                                                         \
    const u16* _s = Ag + (size_t)((h) * 128 + srow) * K + ((c) << 6) + schunk * 8; \
    u16* _d = lds + (((c) & 1) << 15) + (h) * 8192 + tid * 8;                  \
    gload16(_s, _d);                                                           \
    gload16(_s + (size_t)64 * K, _d + 4096);                                   \
  } while (0)
#define STAGE_B(c, h)                                                          \
  do {                                                                         \
    const u16* _s = Bg + (size_t)((h) * 128 + srow) * K + ((c) << 6) + schunk * 8; \
    u16* _d = lds + (((c) & 1) << 15) + 16384 + (h) * 8192 + tid * 8;          \
    gload16(_s, _d);                                                           \
    gload16(_s + (size_t)64 * K, _d + 4096);                                   \
  } while (0)

  const int c0s = (kq ^ (lr & 7)) << 3;         // swizzled chunk offset, kk=0
  const int c1s = ((4 + kq) ^ (lr & 7)) << 3;   // kk=1
  const int aRowBase = (wm * 128 + lr) * 64;
  const int bRowBase = (wn * 64 + lr) * 64;

  short8 afr[4][2];      // current m-half fragments
  short8 bfr[2][2][2];   // [nh][ni][kk]
  f32x4 acc[8][4] = {};

  auto LDA = [&](int buf, int mh) {
    #pragma unroll
    for (int mi = 0; mi < 4; ++mi) {
      const u16* p = lds + (buf << 15) + aRowBase + (mh * 64 + mi * 16) * 64;
      afr[mi][0] = *(const short8*)(p + c0s);
      afr[mi][1] = *(const short8*)(p + c1s);
    }
  };
  auto LDB = [&](int buf, int nh) {
    #pragma unroll
    for (int ni = 0; ni < 2; ++ni) {
      const u16* p = lds + (buf << 15) + 16384 + bRowBase + ((nh * 2 + ni) * 16) * 64;
      bfr[nh][ni][0] = *(const short8*)(p + c0s);
      bfr[nh][ni][1] = *(const short8*)(p + c1s);
    }
  };
  auto MMA = [&](int mh, int nh) {
    __builtin_amdgcn_s_setprio(1);
    #pragma unroll
    for (int mi = 0; mi < 4; ++mi) {
      #pragma unroll
      for (int ni = 0; ni < 2; ++ni) {
        int m = mh * 4 + mi, n = nh * 2 + ni;
        acc[m][n] = __builtin_amdgcn_mfma_f32_16x16x32_bf16(afr[mi][0], bfr[nh][ni][0], acc[m][n], 0, 0, 0);
        acc[m][n] = __builtin_amdgcn_mfma_f32_16x16x32_bf16(afr[mi][1], bfr[nh][ni][1], acc[m][n], 0, 0, 0);
      }
    }
    __builtin_amdgcn_s_setprio(0);
  };

  // ---- prologue: stage K-tile 0 fully + B of K-tile 1 (FIFO: B0,A0,B1) ----
  STAGE_B(0, 0); STAGE_B(0, 1);
  STAGE_A(0, 0); STAGE_A(0, 1);
  STAGE_B(1, 0); STAGE_B(1, 1);
  asm volatile("s_waitcnt vmcnt(4)" ::: "memory");  // K-tile 0 landed
  BAR();

  const int NITER = K >> 7;   // 2 K-tiles (128 of K) per iteration
  for (int i = 0; i < NITER; ++i) {
    const int g = (i + 1 < NITER);
    const int cA = 2 * i + 1, c2 = 2 * i + 2, c3 = 2 * i + 3;

    // ---- K-tile 2i from buf0 ----
    // p0
    LDA(0, 0); LDB(0, 0);
    STAGE_A(cA, 0);
    BAR(); MMA(0, 0); BAR();
    // p1
    LDB(0, 1);
    STAGE_A(cA, 1);
    BAR(); MMA(0, 1); BAR();
    // p2
    LDA(0, 1);
    if (g) STAGE_B(c2, 0);
    BAR(); MMA(1, 1); BAR();
    // p3
    if (g) {
      STAGE_B(c2, 1);
      asm volatile("s_waitcnt vmcnt(4)" ::: "memory");
    } else {
      asm volatile("s_waitcnt vmcnt(0)" ::: "memory");
    }
    BAR(); MMA(1, 0); BAR();

    // ---- K-tile 2i+1 from buf1 ----
    // p4
    LDA(1, 0); LDB(1, 0);
    if (g) STAGE_A(c2, 0);
    BAR(); MMA(0, 0); BAR();
    // p5
    LDB(1, 1);
    if (g) STAGE_A(c2, 1);
    BAR(); MMA(0, 1); BAR();
    // p6
    LDA(1, 1);
    if (g) STAGE_B(c3, 0);
    BAR(); MMA(1, 1); BAR();
    // p7
    if (g) {
      STAGE_B(c3, 1);
      asm volatile("s_waitcnt vmcnt(4)" ::: "memory");
    }
    BAR(); MMA(1, 0); BAR();
  }
#undef STAGE_A
#undef STAGE_B

  // ---- epilogue ----
  const int rowB = mt * 256 + wm * 128 + kq * 4;
  const int colB = nt * 256 + wn * 64 + lr;
  #pragma unroll
  for (int m = 0; m < 8; ++m) {
    #pragma unroll
    for (int n = 0; n < 4; ++n) {
      #pragma unroll
      for (int j = 0; j < 4; ++j) {
        int row = rowB + m * 16 + j;
        int col = colB + n * 16;
        size_t idx = (size_t)row * N + col;
        float v = acc[m][n][j];
        if constexpr (MODE == 0) {
          ((u16*)Cptr)[idx] = f2bf(v);
        } else if constexpr (MODE == 1) {
          ((float*)Cptr)[idx] = 1.0f / (1.0f + __expf(-v));
        } else {
          float* O = (float*)Cptr;
          O[idx] = O[idx] * v;
        }
      }
    }
  }
}

// ---------------- K3: L2-normalize(q head) @ S[b,h] -> RMSNorm -> bf16 o_mid ----------------
__global__ __launch_bounds__(256) void glaread_k(const u16* __restrict__ q,
                                                 const float* __restrict__ S,
                                                 const float* __restrict__ vw,
                                                 u16* __restrict__ omid) {
  int bh = blockIdx.x;             // b*16 + h
  int b = bh >> 4, h = bh & 15;
  int tid = threadIdx.x;
  int w = tid >> 6, l = tid & 63;
  int lr = l & 15, kq = l >> 4;

  const float* Sp = S + (size_t)bh * HEADK * HEADV;
  short8 bfrag[8][2];
  #pragma unroll
  for (int n = 0; n < 8; ++n) {
    #pragma unroll
    for (int s = 0; s < 2; ++s) {
      #pragma unroll
      for (int i = 0; i < 8; ++i)
        bfrag[n][s][i] =
            (short)f2bf(Sp[(size_t)(s * 32 + kq * 8 + i) * HEADV + n * 16 + lr]);
    }
  }
  float vwn[8];
  #pragma unroll
  for (int n = 0; n < 8; ++n) vwn[n] = vw[n * 16 + lr];

  #pragma unroll 1
  for (int it = 0; it < 8; ++it) {
    int t0 = blockIdx.y * 512 + it * 64 + w * 16;
    const u16* qp = q + (size_t)(b * SEQ + t0 + lr) * KEYDIM + h * HEADK;
    short8 a0 = *(const short8*)(qp + kq * 8);
    short8 a1 = *(const short8*)(qp + 32 + kq * 8);

    float ss = 0.f;
    #pragma unroll
    for (int i = 0; i < 8; ++i) {
      float x0 = bf2f((u16)a0[i]), x1 = bf2f((u16)a1[i]);
      ss += x0 * x0 + x1 * x1;
    }
    ss += __shfl_xor(ss, 16);
    ss += __shfl_xor(ss, 32);
    float sc = 1.0f / fmaxf(sqrtf(ss), 1e-12f);

    short8 an0, an1;
    #pragma unroll
    for (int i = 0; i < 8; ++i) {
      an0[i] = (short)f2bf(bf2f((u16)a0[i]) * sc);
      an1[i] = (short)f2bf(bf2f((u16)a1[i]) * sc);
    }

    f32x4 acc[8] = {};
    #pragma unroll
    for (int n = 0; n < 8; ++n) {
      acc[n] = __builtin_amdgcn_mfma_f32_16x16x32_bf16(an0, bfrag[n][0], acc[n], 0, 0, 0);
      acc[n] = __builtin_amdgcn_mfma_f32_16x16x32_bf16(an1, bfrag[n][1], acc[n], 0, 0, 0);
    }

    float part[4] = {0.f, 0.f, 0.f, 0.f};
    #pragma unroll
    for (int n = 0; n < 8; ++n) {
      #pragma unroll
      for (int j = 0; j < 4; ++j) part[j] += acc[n][j] * acc[n][j];
    }
    #pragma unroll
    for (int msk = 1; msk <= 8; msk <<= 1) {
      #pragma unroll
      for (int j = 0; j < 4; ++j) part[j] += __shfl_xor(part[j], msk);
    }
    #pragma unroll
    for (int j = 0; j < 4; ++j) {
      float inv = rsqrtf(part[j] * (1.0f / HEADV) + 1e-5f);
      int tok = t0 + kq * 4 + j;
      u16* op = omid + (size_t)(b * SEQ + tok) * VALDIM + h * HEADV;
      #pragma unroll
      for (int n = 0; n < 8; ++n)
        op[n * 16 + lr] = f2bf(acc[n][j] * inv * vwn[n]);
    }
  }
}

extern "C" void kernel_launch(void* const* d_in, const int* in_sizes, int n_in,
                              void* d_out, int out_size, void* d_ws, size_t ws_size,
                              hipStream_t stream) {
  const float* hs = (const float*)d_in[0];   // (8,4096,2048)
  const float* S  = (const float*)d_in[1];   // (8,16,64,128)
  const float* nw = (const float*)d_in[2];   // (2048)
  const float* qw = (const float*)d_in[3];   // (1024,2048)
  const float* vw = (const float*)d_in[4];   // (128)
  const float* ow = (const float*)d_in[5];   // (2048,2048)
  const float* gw = (const float*)d_in[6];   // (2048,2048)
  float* out = (float*)d_out;

  u16* xb   = (u16*)d_ws;                             // NTOK*2048 bf16
  u16* q    = xb + (size_t)NTOK * HIDDEN;             // NTOK*1024 bf16
  u16* qwb  = q + (size_t)NTOK * KEYDIM;              // 1024*2048
  u16* owb  = qwb + (size_t)KEYDIM * HIDDEN;          // 2048*2048
  u16* gwb  = owb + (size_t)HIDDEN * VALDIM;          // 2048*2048
  u16* omid = xb;  // reuse xb after gate GEMM has consumed it

  const size_t LDSB = 131072;  // 128 KiB

  // weight casts
  cast_bf16_k<<<(KEYDIM * HIDDEN / 4 + 255) / 256, 256, 0, stream>>>(qw, qwb, KEYDIM * HIDDEN / 4);
  cast_bf16_k<<<(HIDDEN * VALDIM / 4 + 255) / 256, 256, 0, stream>>>(ow, owb, HIDDEN * VALDIM / 4);
  cast_bf16_k<<<(HIDDEN * HIDDEN / 4 + 255) / 256, 256, 0, stream>>>(gw, gwb, HIDDEN * HIDDEN / 4);

  // x = rmsnorm(hidden) -> bf16
  rmsnorm_cast_k<<<NTOK, 256, 0, stream>>>(hs, nw, xb);

  // q = x @ q_w^T  (bf16 out)
  gemm8p_k<0><<<dim3((NTOK / 256) * (KEYDIM / 256)), 512, LDSB, stream>>>(xb, qwb, q, NTOK, KEYDIM, HIDDEN);

  // out = sigmoid(x @ gate_w^T)  (f32)
  gemm8p_k<1><<<dim3((NTOK / 256) * (HIDDEN / 256)), 512, LDSB, stream>>>(xb, gwb, out, NTOK, HIDDEN, HIDDEN);

  // o_mid = rmsnorm_v( l2norm(q_head) @ S[b,h] )  (bf16, overwrites xb)
  glaread_k<<<dim3(NBATCH * NHEADS, SEQ / 512), 256, 0, stream>>>(q, S, vw, omid);

  // out *= o_mid @ o_w^T
  gemm8p_k<2><<<dim3((NTOK / 256) * (HIDDEN / 256)), 512, LDSB, stream>>>(omid, owb, out, NTOK, HIDDEN, VALDIM);
}